// Round 7
// baseline (330.996 us; speedup 1.0000x reference)
//
#include <hip/hip_runtime.h>
#include <hip/hip_bf16.h>

// AssignAttention: B=16, N=256, S=4096, C=512, H=8, hd=64
// out[b,n,h*64+c] = sum_s softmax_n(q.kT/8)[n,s]/max(rowsum,1) * key[b,s,h*64+c]
// d_out = [out, out_style] (identical copies), fp32.

typedef __attribute__((ext_vector_type(8))) short bf16x8;
typedef __attribute__((ext_vector_type(4))) float f32x4;
typedef unsigned int u32;

__device__ __forceinline__ unsigned short f2bf(float f) {
  union { __hip_bfloat16 h; unsigned short u; } cv;
  cv.h = __float2bfloat16(f);
  return cv.u;
}

__device__ __forceinline__ u32 pkbf(float a, float b) {   // low=bf(a), high=bf(b)
  union { __hip_bfloat162 h; u32 u; } cv;
  cv.h = __float22bfloat162_rn(float2{a, b});
  return cv.u;
}

// async global->LDS, 16B per lane. LDS dest = wave-uniform base + lane*16.
__device__ __forceinline__ void async_copy16(const void* gptr, void* lptr) {
  __builtin_amdgcn_global_load_lds((const __attribute__((address_space(1))) u32*)gptr,
                                   (__attribute__((address_space(3))) u32*)lptr,
                                   16, 0, 0);
}

// ---------------------------------------------------------------- prep: Wt[n][k] = bf16(W[k][n])  (+ optional bf16 casts)
// blk < 128:               W-transpose (as before)
// 128 <= blk < 128+16384:  key fp32 -> bf16 cast (kcast), 8 elems/thread
// blk >= 128+16384:        query fp32 -> bf16 cast (qcast)
__global__ __launch_bounds__(256) void prep_w(const float* __restrict__ Wq,
                                              const float* __restrict__ Wk,
                                              unsigned short* __restrict__ WtQ,
                                              unsigned short* __restrict__ WtK,
                                              const float* __restrict__ key,
                                              unsigned short* __restrict__ kcast,
                                              const float* __restrict__ query,
                                              unsigned short* __restrict__ qcast) {
  __shared__ float tile[64][65];
  const int blk = blockIdx.x;
  const int t = threadIdx.x;
  if (blk >= 128) {
    const float* src; unsigned short* dst; size_t idx;
    if (blk < 128 + 16384) { src = key;   dst = kcast; idx = ((size_t)(blk - 128) * 256 + t) * 8; }
    else                   { src = query; dst = qcast; idx = ((size_t)(blk - 16512) * 256 + t) * 8; }
    float4 u = *reinterpret_cast<const float4*>(&src[idx]);
    float4 v = *reinterpret_cast<const float4*>(&src[idx + 4]);
    uint4 w;
    w.x = pkbf(u.x, u.y); w.y = pkbf(u.z, u.w);
    w.z = pkbf(v.x, v.y); w.w = pkbf(v.z, v.w);
    *reinterpret_cast<uint4*>(&dst[idx]) = w;
    return;
  }
  const float* W = (blk & 1) ? Wk : Wq;
  unsigned short* Wt = (blk & 1) ? WtK : WtQ;
  const int tb = blk >> 1;                     // 0..63
  const int k0 = (tb >> 3) * 64, n0 = (tb & 7) * 64;
  const int row = t >> 4, col4 = (t & 15) * 4;
#pragma unroll
  for (int i = 0; i < 4; ++i) {
    int r = i * 16 + row;
    float4 v = *reinterpret_cast<const float4*>(&W[(size_t)(k0 + r) * 512 + n0 + col4]);
    tile[r][col4 + 0] = v.x; tile[r][col4 + 1] = v.y;
    tile[r][col4 + 2] = v.z; tile[r][col4 + 3] = v.w;
  }
  __syncthreads();
#pragma unroll
  for (int i = 0; i < 4; ++i) {
    int r = i * 16 + row;                      // n-local output row
    short4 s;
    s.x = (short)f2bf(tile[col4 + 0][r]);
    s.y = (short)f2bf(tile[col4 + 1][r]);
    s.z = (short)f2bf(tile[col4 + 2][r]);
    s.w = (short)f2bf(tile[col4 + 3][r]);
    *reinterpret_cast<short4*>(&Wt[(size_t)(n0 + r) * 512 + k0 + col4]) = s;
  }
}

// ---------------------------------------------------------------- GEMM (new): Y = bf16A @ WtT, pure-DMA 2-phase
// Minimum 2-phase pipeline (T3 recipe): dbuf As/Bs, ONE __syncthreads per
// k-step; STAGE(it+1) issued right after the barrier so its DMA flies across
// compute(it) and is drained by the next barrier's implicit vmcnt(0).
// No cvt, no reg staging, no publish phase. A and B staged identically
// (swizzled source -> linear LDS dest = swizzled chunks, conflict-free).
__global__ __launch_bounds__(256, 2) void gemm_bb(const unsigned short* __restrict__ Ak,
                                                  const unsigned short* __restrict__ WtKp,
                                                  __hip_bfloat16* __restrict__ Yk,
                                                  const unsigned short* __restrict__ Aq,
                                                  const unsigned short* __restrict__ WtQp,
                                                  __hip_bfloat16* __restrict__ Yq) {
  __shared__ unsigned short As[2][128 * 64];     // 2x16 KB
  __shared__ unsigned short Bs[2][128 * 64];     // 2x16 KB
  const int t = threadIdx.x;
  const int wave = t >> 6, lane = t & 63, l15 = lane & 15, quad = lane >> 4;

  // XCD-bijective swizzle over the merged grid (nwg=2176, %8==0).
  const int nwg = gridDim.x * gridDim.y;
  const int d = blockIdx.y * gridDim.x + blockIdx.x;
  const int tile = (d & 7) * (nwg >> 3) + (d >> 3);

  const unsigned short* A; const unsigned short* Wt; __hip_bfloat16* Y; int n0, m0;
  if (tile < 2048) { A = Ak; Wt = WtKp; Y = Yk; n0 = (tile & 3) * 128; m0 = (tile >> 2) * 128; }
  else { int u = tile - 2048; A = Aq; Wt = WtQp; Y = Yq; n0 = (u & 3) * 128; m0 = (u >> 2) * 128; }

  const int wm = (wave >> 1) * 64, wn = (wave & 1) * 64;
  const int rl = lane >> 3;                       // 0..7
  const int cs = (lane & 7) ^ rl;                 // source chunk (row&7 == rl)

  const unsigned short* Abase = A + (size_t)m0 * 512;
  const unsigned short* Bbase = Wt + (size_t)n0 * 512;

  f32x4 acc[4][4];
#pragma unroll
  for (int i = 0; i < 4; ++i)
#pragma unroll
    for (int j = 0; j < 4; ++j) { f32x4 z = {0.f, 0.f, 0.f, 0.f}; acc[i][j] = z; }

#define STAGE_BB(kt, S_) do {                                                        \
    const unsigned short* aB_ = Abase + (kt) * 64;                                   \
    const unsigned short* bB_ = Bbase + (kt) * 64;                                   \
    _Pragma("unroll")                                                                \
    for (int o_ = 0; o_ < 4; ++o_) {                                                 \
      int rg_ = wave * 4 + o_;                                                       \
      async_copy16(aB_ + (size_t)(rg_ * 8 + rl) * 512 + cs * 8, &As[S_][rg_ * 512]); \
      async_copy16(bB_ + (size_t)(rg_ * 8 + rl) * 512 + cs * 8, &Bs[S_][rg_ * 512]); \
    }                                                                                \
  } while (0)

  STAGE_BB(0, 0);

#pragma unroll 2
  for (int it = 0; it < 8; ++it) {
    const int S = it & 1;
    __syncthreads();                   // drains STAGE(it) [flew across compute(it-1)]; retires compute(it-1)
    if (it < 7) STAGE_BB(it + 1, S ^ 1);
    __builtin_amdgcn_sched_barrier(0); // keep the stage issue above compute

#pragma unroll
    for (int x = 0; x < 2; ++x) {
      bf16x8 a[4], bfr[4];
#pragma unroll
      for (int i = 0; i < 4; ++i) {
        int ra = wm + 16 * i + l15;
        a[i] = *reinterpret_cast<const bf16x8*>(&As[S][ra * 64 + (((x * 4 + quad) ^ (ra & 7)) << 3)]);
      }
#pragma unroll
      for (int j = 0; j < 4; ++j) {
        int rb = wn + 16 * j + l15;
        bfr[j] = *reinterpret_cast<const bf16x8*>(&Bs[S][rb * 64 + (((x * 4 + quad) ^ (rb & 7)) << 3)]);
      }
#pragma unroll
      for (int i = 0; i < 4; ++i)
#pragma unroll
        for (int j = 0; j < 4; ++j)
          acc[i][j] = __builtin_amdgcn_mfma_f32_16x16x32_bf16(a[i], bfr[j], acc[i][j], 0, 0, 0);
    }
  }
#undef STAGE_BB

#pragma unroll
  for (int i = 0; i < 4; ++i)
#pragma unroll
    for (int j = 0; j < 4; ++j)
#pragma unroll
      for (int r = 0; r < 4; ++r) {
        int m = m0 + wm + 16 * i + 4 * quad + r;
        int n = n0 + wn + 16 * j + l15;
        Y[(size_t)m * 512 + n] = __float2bfloat16(acc[i][j][r]);
      }
}

// ---------------------------------------------------------------- GEMM (fallback, R6 path): Y = bf16( X_fp32 @ Wt )
__global__ __launch_bounds__(256, 2) void gemm_xw(const float* __restrict__ Xk,
                                                  const unsigned short* __restrict__ WtKp,
                                                  __hip_bfloat16* __restrict__ Yk,
                                                  const float* __restrict__ Xq,
                                                  const unsigned short* __restrict__ WtQp,
                                                  __hip_bfloat16* __restrict__ Yq) {
  __shared__ unsigned short As[2][128 * 64];
  __shared__ unsigned short Bs[2][128 * 64];
  const int t = threadIdx.x;
  const int wave = t >> 6, lane = t & 63, l15 = lane & 15, quad = lane >> 4;

  const int nwg = gridDim.x * gridDim.y;               // 2176
  const int d = blockIdx.y * gridDim.x + blockIdx.x;
  const int tile = (d & 7) * (nwg >> 3) + (d >> 3);

  const float* X; const unsigned short* Wt; __hip_bfloat16* Y; int n0, m0;
  if (tile < 2048) { X = Xk; Wt = WtKp; Y = Yk; n0 = (tile & 3) * 128; m0 = (tile >> 2) * 128; }
  else { int u = tile - 2048; X = Xq; Wt = WtQp; Y = Yq; n0 = (u & 3) * 128; m0 = (u >> 2) * 128; }

  const int wm = (wave >> 1) * 64, wn = (wave & 1) * 64;
  const int b_rl = lane >> 3;
  const int b_cs = (lane & 7) ^ b_rl;
  const int cr = t >> 3, cc = t & 7;

  f32x4 acc[4][4];
#pragma unroll
  for (int i = 0; i < 4; ++i)
#pragma unroll
    for (int j = 0; j < 4; ++j) { f32x4 z = {0.f, 0.f, 0.f, 0.f}; acc[i][j] = z; }

  float4 fA[2][4][2];

#define ISSUE_B(kt) do {                                                             \
    const int S_ = (kt) & 1; const int kk_ = (kt) * 64;                              \
    const unsigned short* bB_ = Wt + (size_t)n0 * 512 + kk_;                         \
    _Pragma("unroll")                                                                \
    for (int o_ = 0; o_ < 4; ++o_) {                                                 \
      int rg_ = wave * 4 + o_;                                                       \
      async_copy16(bB_ + (size_t)(rg_ * 8 + b_rl) * 512 + b_cs * 8,                  \
                   &Bs[S_][rg_ * 512]);                                              \
    }                                                                                \
  } while (0)

#define ISSUE_A(kt) do {                                                             \
    const int S_ = (kt) & 1; const int kk_ = (kt) * 64;                              \
    const float* aB_ = X + (size_t)m0 * 512 + kk_;                                   \
    _Pragma("unroll")                                                                \
    for (int i_ = 0; i_ < 4; ++i_) {                                                 \
      const float* p_ = aB_ + (size_t)(i_ * 32 + cr) * 512 + cc * 8;                 \
      fA[S_][i_][0] = *reinterpret_cast<const float4*>(p_);                          \
      fA[S_][i_][1] = *reinterpret_cast<const float4*>(p_ + 4);                      \
    }                                                                                \
  } while (0)

#define CVT_PUB(kt) do {                                                             \
    const int S_ = (kt) & 1;                                                         \
    _Pragma("unroll")                                                                \
    for (int i_ = 0; i_ < 4; ++i_) {                                                 \
      uint4 w_;                                                                      \
      w_.x = pkbf(fA[S_][i_][0].x, fA[S_][i_][0].y);                                 \
      w_.y = pkbf(fA[S_][i_][0].z, fA[S_][i_][0].w);                                 \
      w_.z = pkbf(fA[S_][i_][1].x, fA[S_][i_][1].y);                                 \
      w_.w = pkbf(fA[S_][i_][1].z, fA[S_][i_][1].w);                                 \
      int r_ = i_ * 32 + cr;                                                         \
      *reinterpret_cast<uint4*>(&As[S_][r_ * 64 + ((cc ^ (r_ & 7)) << 3)]) = w_;     \
    }                                                                                \
  } while (0)

#define COMPUTE(kt) do {                                                             \
    const int S_ = (kt) & 1;                                                         \
    _Pragma("unroll")                                                                \
    for (int x_ = 0; x_ < 2; ++x_) {                                                 \
      bf16x8 a_[4], b_[4];                                                           \
      _Pragma("unroll")                                                              \
      for (int i_ = 0; i_ < 4; ++i_) {                                               \
        int ra_ = wm + 16 * i_ + l15;                                                \
        a_[i_] = *reinterpret_cast<const bf16x8*>(                                   \
            &As[S_][ra_ * 64 + (((x_ * 4 + quad) ^ (ra_ & 7)) << 3)]);               \
      }                                                                              \
      _Pragma("unroll")                                                              \
      for (int j_ = 0; j_ < 4; ++j_) {                                               \
        int rb_ = wn + 16 * j_ + l15;                                                \
        b_[j_] = *reinterpret_cast<const bf16x8*>(                                   \
            &Bs[S_][rb_ * 64 + (((x_ * 4 + quad) ^ (rb_ & 7)) << 3)]);               \
      }                                                                              \
      _Pragma("unroll")                                                              \
      for (int i_ = 0; i_ < 4; ++i_)                                                 \
        _Pragma("unroll")                                                            \
        for (int j_ = 0; j_ < 4; ++j_)                                               \
          acc[i_][j_] =                                                              \
              __builtin_amdgcn_mfma_f32_16x16x32_bf16(a_[i_], b_[j_], acc[i_][j_],   \
                                                      0, 0, 0);                      \
    }                                                                                \
  } while (0)

  ISSUE_B(0);
  __builtin_amdgcn_sched_barrier(0);
  ISSUE_A(0);
  __builtin_amdgcn_sched_barrier(0);
  ISSUE_A(1);
  __builtin_amdgcn_sched_barrier(0);
  CVT_PUB(0);
  asm volatile("s_waitcnt vmcnt(8)" ::: "memory");
  asm volatile("s_waitcnt lgkmcnt(0)" ::: "memory");
  __builtin_amdgcn_sched_barrier(0);
  __builtin_amdgcn_s_barrier();
  __builtin_amdgcn_sched_barrier(0);

#pragma unroll
  for (int it = 0; it < 8; ++it) {
    if (it < 7) { ISSUE_B(it + 1); __builtin_amdgcn_sched_barrier(0); }
    if (it < 6) { ISSUE_A(it + 2); __builtin_amdgcn_sched_barrier(0); }

    COMPUTE(it);

    if (it < 7) {
      CVT_PUB(it + 1);
      if (it < 6) asm volatile("s_waitcnt vmcnt(8)" ::: "memory");
      else        asm volatile("s_waitcnt vmcnt(0)" ::: "memory");
      asm volatile("s_waitcnt lgkmcnt(0)" ::: "memory");
      __builtin_amdgcn_sched_barrier(0);
      __builtin_amdgcn_s_barrier();
      __builtin_amdgcn_sched_barrier(0);
    }
  }

#undef ISSUE_B
#undef ISSUE_A
#undef CVT_PUB
#undef COMPUTE

#pragma unroll
  for (int i = 0; i < 4; ++i)
#pragma unroll
    for (int j = 0; j < 4; ++j)
#pragma unroll
      for (int r = 0; r < 4; ++r) {
        int m = m0 + wm + 16 * i + 4 * quad + r;
        int n = n0 + wn + 16 * j + l15;
        Y[(size_t)m * 512 + n] = __float2bfloat16(acc[i][j][r]);
      }
}

// ---------------------------------------------------------------- fused attention (swapped-operand)
// USEBF: V read from pre-cast bf16 key (vcast); else from fp32 keyg.
template<bool USEBF>
__global__ __launch_bounds__(512, 2) void attn_kernel(const __hip_bfloat16* __restrict__ qg,
                                                      const __hip_bfloat16* __restrict__ kg,
                                                      const float* __restrict__ keyg,
                                                      const unsigned short* __restrict__ vcast,
                                                      float* __restrict__ accg,
                                                      float* __restrict__ rsg) {
  __shared__ unsigned short qs[256 * 64];    // q[n][c], 16B-chunk phys = cc ^ (n&7)   (32 KB)
  __shared__ unsigned short vs[64 * 128];    // v^T[c][s], chunk phys = sc ^ (c&7)     (16 KB)
  __shared__ unsigned short pst[256 * 128];  // P[n][s],  chunk phys = sc ^ (n&7)      (64 KB)

  const int t = threadIdx.x;
  const int wave = t >> 6, lane = t & 63, l15 = lane & 15, quad = lane >> 4;
  const int blk = blockIdx.x, chunk = blk & 1, bh = blk >> 1, b = bh >> 3, h = bh & 7;
  const int l7 = l15 & 7;

  // ---- stage qs (once): 4 b128 per thread, coalesced 128B segments
  {
    const unsigned short* qbase = (const unsigned short*)qg + (size_t)(b * 256) * 512 + h * 64;
#pragma unroll
    for (int i = 0; i < 4; ++i) {
      int lin = i * 512 + t;
      int n = lin >> 3, cc = lin & 7, phys = cc ^ (n & 7);
      bf16x8 v = *reinterpret_cast<const bf16x8*>(qbase + (size_t)n * 512 + cc * 8);
      *reinterpret_cast<bf16x8*>(&qs[n * 64 + phys * 8]) = v;
    }
  }

  const unsigned short* kbase = (const unsigned short*)kg + (size_t)(b * 4096 + chunk * 2048) * 512 + h * 64;
  const float* vbase = keyg + (size_t)(b * 4096 + chunk * 2048) * 512 + h * 64;
  const unsigned short* vbase_h = vcast + (size_t)(b * 4096 + chunk * 2048) * 512 + h * 64;

  // ---- prefetch k (regs) and v (regs) for it=0
  bf16x8 kc0 = *reinterpret_cast<const bf16x8*>(kbase + (size_t)(16 * wave + l15) * 512 + quad * 8);
  bf16x8 kc1 = *reinterpret_cast<const bf16x8*>(kbase + (size_t)(16 * wave + l15) * 512 + 32 + quad * 8);
  float vf[16];
  unsigned short vh[16];
#pragma unroll
  for (int half = 0; half < 2; ++half) {
    int sc = wave + 8 * half;
#pragma unroll
    for (int j = 0; j < 8; ++j) {
      if constexpr (USEBF) vh[half * 8 + j] = vbase_h[(size_t)(sc * 8 + j) * 512 + lane];
      else                 vf[half * 8 + j] = vbase[(size_t)(sc * 8 + j) * 512 + lane];
    }
  }

  union { bf16x8 f; int w[4]; } ones_u;
  ones_u.w[0] = 0x3F803F80; ones_u.w[1] = 0x3F803F80;
  ones_u.w[2] = 0x3F803F80; ones_u.w[3] = 0x3F803F80;
  const bf16x8 ones = ones_u.f;

  f32x4 oacc[2][4], rsacc[2];
#pragma unroll
  for (int i = 0; i < 2; ++i) {
    f32x4 z = {0.f, 0.f, 0.f, 0.f};
    rsacc[i] = z;
#pragma unroll
    for (int j = 0; j < 4; ++j) oacc[i][j] = z;
  }

  __syncthreads();   // qs visible

  for (int it = 0; it < 16; ++it) {
    // ---- QK^T (swapped): L[jt] = D[s16 x n16], A = k regs, B = q from LDS
    f32x4 L[16];
#pragma unroll
    for (int jt = 0; jt < 16; ++jt) { f32x4 z = {0.f, 0.f, 0.f, 0.f}; L[jt] = z; }
#pragma unroll
    for (int x = 0; x < 2; ++x) {
      bf16x8 kf = x ? kc1 : kc0;
#pragma unroll
      for (int jt = 0; jt < 16; ++jt) {
        bf16x8 bq = *reinterpret_cast<const bf16x8*>(
            &qs[(16 * jt + l15) * 64 + ((4 * x + quad) ^ l7) * 8]);
        L[jt] = __builtin_amdgcn_mfma_f32_16x16x32_bf16(kf, bq, L[jt], 0, 0, 0);
      }
    }

    // ---- prefetch next k (old regs dead)
    const int nit = (it < 15) ? it + 1 : 15;
    kc0 = *reinterpret_cast<const bf16x8*>(kbase + (size_t)(nit * 128 + 16 * wave + l15) * 512 + quad * 8);
    kc1 = *reinterpret_cast<const bf16x8*>(kbase + (size_t)(nit * 128 + 16 * wave + l15) * 512 + 32 + quad * 8);

    // ---- exp + within-wave column softmax (sum over n = jt in-lane + shfl over l15)
    float cs0 = 0.f, cs1 = 0.f, cs2 = 0.f, cs3 = 0.f;
#pragma unroll
    for (int jt = 0; jt < 16; ++jt) {
      float e0 = __expf(L[jt][0] * 0.125f);
      float e1 = __expf(L[jt][1] * 0.125f);
      float e2 = __expf(L[jt][2] * 0.125f);
      float e3 = __expf(L[jt][3] * 0.125f);
      L[jt][0] = e0; L[jt][1] = e1; L[jt][2] = e2; L[jt][3] = e3;
      cs0 += e0; cs1 += e1; cs2 += e2; cs3 += e3;
    }
#pragma unroll
    for (int m = 1; m <= 8; m <<= 1) {
      cs0 += __shfl_xor(cs0, m);
      cs1 += __shfl_xor(cs1, m);
      cs2 += __shfl_xor(cs2, m);
      cs3 += __shfl_xor(cs3, m);
    }
    const float ri0 = 1.0f / cs0, ri1 = 1.0f / cs1, ri2 = 1.0f / cs2, ri3 = 1.0f / cs3;

    __syncthreads();   // SYNC1: prev iteration's PV readers done with vs/pst

    // ---- stage vs from prefetched regs: one b128 per half, chunk-swizzled
#pragma unroll
    for (int half = 0; half < 2; ++half) {
      int sc = wave + 8 * half;
      uint4 w;
      if constexpr (USEBF) {
        w.x = (u32)vh[half * 8 + 0] | ((u32)vh[half * 8 + 1] << 16);
        w.y = (u32)vh[half * 8 + 2] | ((u32)vh[half * 8 + 3] << 16);
        w.z = (u32)vh[half * 8 + 4] | ((u32)vh[half * 8 + 5] << 16);
        w.w = (u32)vh[half * 8 + 6] | ((u32)vh[half * 8 + 7] << 16);
      } else {
        w.x = pkbf(vf[half * 8 + 0], vf[half * 8 + 1]);
        w.y = pkbf(vf[half * 8 + 2], vf[half * 8 + 3]);
        w.z = pkbf(vf[half * 8 + 4], vf[half * 8 + 5]);
        w.w = pkbf(vf[half * 8 + 6], vf[half * 8 + 7]);
      }
      *reinterpret_cast<uint4*>(&vs[lane * 128 + (sc ^ (lane & 7)) * 8]) = w;
    }

    // ---- write P[n][s] (A-layout rows), b64 chunk-swizzled
    {
      const int scw = 2 * wave + (quad >> 1);           // 16B-chunk of this lane's s
      const int half8 = (quad & 1) * 4;                 // b64 half within chunk
#pragma unroll
      for (int jt = 0; jt < 16; ++jt) {
        uint2 w;
        w.x = pkbf(L[jt][0] * ri0, L[jt][1] * ri1);
        w.y = pkbf(L[jt][2] * ri2, L[jt][3] * ri3);
        int row = 16 * jt + l15;
        *reinterpret_cast<uint2*>(&pst[row * 128 + ((scw ^ l7) * 8) + half8]) = w;
      }
    }

    __syncthreads();   // SYNC2: vs + pst visible

    // ---- prefetch next v (consumed next iteration)
#pragma unroll
    for (int half = 0; half < 2; ++half) {
      int sc = wave + 8 * half;
#pragma unroll
      for (int j = 0; j < 8; ++j) {
        if constexpr (USEBF) vh[half * 8 + j] = vbase_h[(size_t)(nit * 128 + sc * 8 + j) * 512 + lane];
        else                 vf[half * 8 + j] = vbase[(size_t)(nit * 128 + sc * 8 + j) * 512 + lane];
      }
    }

    // ---- PV + ones-rowsum, n-partitioned: wave owns jt' = 2w, 2w+1
#pragma unroll
    for (int kc = 0; kc < 4; ++kc) {
      bf16x8 bv[4];
#pragma unroll
      for (int jc = 0; jc < 4; ++jc)
        bv[jc] = *reinterpret_cast<const bf16x8*>(
            &vs[(16 * jc + l15) * 128 + ((4 * kc + quad) ^ l7) * 8]);
#pragma unroll
      for (int jtl = 0; jtl < 2; ++jtl) {
        int rowp = 16 * (2 * wave + jtl) + l15;
        bf16x8 ap = *reinterpret_cast<const bf16x8*>(
            &pst[rowp * 128 + ((4 * kc + quad) ^ l7) * 8]);
#pragma unroll
        for (int jc = 0; jc < 4; ++jc)
          oacc[jtl][jc] = __builtin_amdgcn_mfma_f32_16x16x32_bf16(ap, bv[jc], oacc[jtl][jc], 0, 0, 0);
        rsacc[jtl] = __builtin_amdgcn_mfma_f32_16x16x32_bf16(ap, ones, rsacc[jtl], 0, 0, 0);
      }
    }
  }

  // ---- flush per-chunk partials (disjoint n per wave, disjoint chunk regions)
  float* rsp = rsg + chunk * 32768 + bh * 256;
  if (l15 == 0) {
#pragma unroll
    for (int jtl = 0; jtl < 2; ++jtl)
#pragma unroll
      for (int r = 0; r < 4; ++r)
        rsp[16 * (2 * wave + jtl) + 4 * quad + r] = rsacc[jtl][r];
  }
  float* ap_ = accg + (size_t)chunk * 2097152 + (size_t)bh * 16384;
#pragma unroll
  for (int jtl = 0; jtl < 2; ++jtl)
#pragma unroll
    for (int jc = 0; jc < 4; ++jc)
#pragma unroll
      for (int r = 0; r < 4; ++r)
        ap_[(16 * (2 * wave + jtl) + 4 * quad + r) * 64 + 16 * jc + l15] = oacc[jtl][jc][r];
}

// ---------------------------------------------------------------- finalize: divide + write both outputs (float4)
__global__ __launch_bounds__(256) void finalize(const float* __restrict__ acc,
                                                const float* __restrict__ rs,
                                                float* __restrict__ out) {
  int g = blockIdx.x * 256 + threadIdx.x;     // 0 .. 524287 (x4 elements)
  int c = (g & 15) * 4, n = (g >> 4) & 255, bh = g >> 12;
  int e = g * 4;
  float4 v0 = *reinterpret_cast<const float4*>(&acc[e]);
  float4 v1 = *reinterpret_cast<const float4*>(&acc[e + 2097152]);
  float r = rs[bh * 256 + n] + rs[32768 + bh * 256 + n];
  float inv = 1.0f / fmaxf(r, 1.0f);
  float4 o;
  o.x = (v0.x + v1.x) * inv; o.y = (v0.y + v1.y) * inv;
  o.z = (v0.z + v1.z) * inv; o.w = (v0.w + v1.w) * inv;
  int b = bh >> 3, h = bh & 7;
  size_t oi = ((size_t)(b * 256 + n)) * 512 + h * 64 + c;
  *reinterpret_cast<float4*>(&out[oi]) = o;
  *reinterpret_cast<float4*>(&out[oi + 2097152]) = o;
}

extern "C" void kernel_launch(void* const* d_in, const int* in_sizes, int n_in,
                              void* d_out, int out_size, void* d_ws, size_t ws_size,
                              hipStream_t stream) {
  const float* query = (const float*)d_in[0];   // [16,256,512]
  const float* key   = (const float*)d_in[1];   // [16,4096,512]
  const float* Wq    = (const float*)d_in[2];   // [512,512]
  const float* Wk    = (const float*)d_in[3];   // [512,512]
  float* out = (float*)d_out;
  char* ws = (char*)d_ws;

  // ws layout (bytes):
  unsigned short* WtQ = (unsigned short*)(ws);                 // 512*512*2   = 524288
  unsigned short* WtK = (unsigned short*)(ws + 524288);        // 524288
  __hip_bfloat16* qbf = (__hip_bfloat16*)(ws + 1048576);       // 4096*512*2  = 4194304
  __hip_bfloat16* kbf = (__hip_bfloat16*)(ws + 5242880);       // 65536*512*2 = 67108864
  float* accw = (float*)(ws + 72351744);                       // 2*128*256*64*4 = 16777216
  float* rsw  = (float*)(ws + 89128960);                       // 2*128*256*4    = 262144
  // base total: 89,391,104
  unsigned short* kcast = (unsigned short*)(ws + 89391104);    // 65536*512*2 = 67108864
  unsigned short* qcast = (unsigned short*)(ws + 156499968);   // 4096*512*2  = 4194304
  // extended total: 160,694,272
  const bool usebf = ws_size >= 160694272ull;

  if (usebf) {
    prep_w<<<17536, 256, 0, stream>>>(Wq, Wk, WtQ, WtK, key, kcast, query, qcast);
    gemm_bb<<<dim3(4, 544), 256, 0, stream>>>(kcast, WtK, kbf, qcast, WtQ, qbf);
    attn_kernel<true><<<256, 512, 0, stream>>>(qbf, kbf, key, kcast, accw, rsw);
  } else {
    prep_w<<<128, 256, 0, stream>>>(Wq, Wk, WtQ, WtK, key, nullptr, query, nullptr);
    gemm_xw<<<dim3(4, 544), 256, 0, stream>>>(key, WtK, kbf, query, WtQ, qbf);
    attn_kernel<false><<<256, 512, 0, stream>>>(qbf, kbf, key, nullptr, accw, rsw);
  }
  finalize<<<2048, 256, 0, stream>>>(accw, rsw, out);
}

// Round 8
// 328.922 us; speedup vs baseline: 1.0063x; 1.0063x over previous
//
#include <hip/hip_runtime.h>
#include <hip/hip_bf16.h>

// AssignAttention: B=16, N=256, S=4096, C=512, H=8, hd=64
// out[b,n,h*64+c] = sum_s softmax_n(q.kT/8)[n,s]/max(rowsum,1) * key[b,s,h*64+c]
// d_out = [out, out_style] (identical copies), fp32.

typedef __attribute__((ext_vector_type(8))) short bf16x8;
typedef __attribute__((ext_vector_type(4))) float f32x4;
typedef unsigned int u32;

__device__ __forceinline__ unsigned short f2bf(float f) {
  union { __hip_bfloat16 h; unsigned short u; } cv;
  cv.h = __float2bfloat16(f);
  return cv.u;
}

__device__ __forceinline__ u32 pkbf(float a, float b) {   // low=bf(a), high=bf(b)
  union { __hip_bfloat162 h; u32 u; } cv;
  cv.h = __float22bfloat162_rn(float2{a, b});
  return cv.u;
}

// async global->LDS, 16B per lane. LDS dest = wave-uniform base + lane*16.
__device__ __forceinline__ void async_copy16(const void* gptr, void* lptr) {
  __builtin_amdgcn_global_load_lds((const __attribute__((address_space(1))) u32*)gptr,
                                   (__attribute__((address_space(3))) u32*)lptr,
                                   16, 0, 0);
}

// ---------------------------------------------------------------- prep: Wt[n][k] = bf16(W[k][n])  (+ bf16 casts of key/query)
// blk < 128:               W-transpose
// 128 <= blk < 128+16384:  key fp32 -> bf16 cast (kcast), 8 elems/thread
// blk >= 128+16384:        query fp32 -> bf16 cast (qcast)
__global__ __launch_bounds__(256) void prep_w(const float* __restrict__ Wq,
                                              const float* __restrict__ Wk,
                                              unsigned short* __restrict__ WtQ,
                                              unsigned short* __restrict__ WtK,
                                              const float* __restrict__ key,
                                              unsigned short* __restrict__ kcast,
                                              const float* __restrict__ query,
                                              unsigned short* __restrict__ qcast) {
  __shared__ float tile[64][65];
  const int blk = blockIdx.x;
  const int t = threadIdx.x;
  if (blk >= 128) {
    const float* src; unsigned short* dst; size_t idx;
    if (blk < 128 + 16384) { src = key;   dst = kcast; idx = ((size_t)(blk - 128) * 256 + t) * 8; }
    else                   { src = query; dst = qcast; idx = ((size_t)(blk - 16512) * 256 + t) * 8; }
    float4 u = *reinterpret_cast<const float4*>(&src[idx]);
    float4 v = *reinterpret_cast<const float4*>(&src[idx + 4]);
    uint4 w;
    w.x = pkbf(u.x, u.y); w.y = pkbf(u.z, u.w);
    w.z = pkbf(v.x, v.y); w.w = pkbf(v.z, v.w);
    *reinterpret_cast<uint4*>(&dst[idx]) = w;
    return;
  }
  const float* W = (blk & 1) ? Wk : Wq;
  unsigned short* Wt = (blk & 1) ? WtK : WtQ;
  const int tb = blk >> 1;                     // 0..63
  const int k0 = (tb >> 3) * 64, n0 = (tb & 7) * 64;
  const int row = t >> 4, col4 = (t & 15) * 4;
#pragma unroll
  for (int i = 0; i < 4; ++i) {
    int r = i * 16 + row;
    float4 v = *reinterpret_cast<const float4*>(&W[(size_t)(k0 + r) * 512 + n0 + col4]);
    tile[r][col4 + 0] = v.x; tile[r][col4 + 1] = v.y;
    tile[r][col4 + 2] = v.z; tile[r][col4 + 3] = v.w;
  }
  __syncthreads();
#pragma unroll
  for (int i = 0; i < 4; ++i) {
    int r = i * 16 + row;                      // n-local output row
    short4 s;
    s.x = (short)f2bf(tile[col4 + 0][r]);
    s.y = (short)f2bf(tile[col4 + 1][r]);
    s.z = (short)f2bf(tile[col4 + 2][r]);
    s.w = (short)f2bf(tile[col4 + 3][r]);
    *reinterpret_cast<short4*>(&Wt[(size_t)(n0 + r) * 512 + k0 + col4]) = s;
  }
}

// ---------------------------------------------------------------- GEMM: Y = bf16A @ WtT, pure-DMA 2-phase (R7, verified fast)
__global__ __launch_bounds__(256, 2) void gemm_bb(const unsigned short* __restrict__ Ak,
                                                  const unsigned short* __restrict__ WtKp,
                                                  __hip_bfloat16* __restrict__ Yk,
                                                  const unsigned short* __restrict__ Aq,
                                                  const unsigned short* __restrict__ WtQp,
                                                  __hip_bfloat16* __restrict__ Yq) {
  __shared__ unsigned short As[2][128 * 64];     // 2x16 KB
  __shared__ unsigned short Bs[2][128 * 64];     // 2x16 KB
  const int t = threadIdx.x;
  const int wave = t >> 6, lane = t & 63, l15 = lane & 15, quad = lane >> 4;

  // XCD-bijective swizzle over the merged grid (nwg=2176, %8==0).
  const int nwg = gridDim.x * gridDim.y;
  const int d = blockIdx.y * gridDim.x + blockIdx.x;
  const int tile = (d & 7) * (nwg >> 3) + (d >> 3);

  const unsigned short* A; const unsigned short* Wt; __hip_bfloat16* Y; int n0, m0;
  if (tile < 2048) { A = Ak; Wt = WtKp; Y = Yk; n0 = (tile & 3) * 128; m0 = (tile >> 2) * 128; }
  else { int u = tile - 2048; A = Aq; Wt = WtQp; Y = Yq; n0 = (u & 3) * 128; m0 = (u >> 2) * 128; }

  const int wm = (wave >> 1) * 64, wn = (wave & 1) * 64;
  const int rl = lane >> 3;                       // 0..7
  const int cs = (lane & 7) ^ rl;                 // source chunk (row&7 == rl)

  const unsigned short* Abase = A + (size_t)m0 * 512;
  const unsigned short* Bbase = Wt + (size_t)n0 * 512;

  f32x4 acc[4][4];
#pragma unroll
  for (int i = 0; i < 4; ++i)
#pragma unroll
    for (int j = 0; j < 4; ++j) { f32x4 z = {0.f, 0.f, 0.f, 0.f}; acc[i][j] = z; }

#define STAGE_BB(kt, S_) do {                                                        \
    const unsigned short* aB_ = Abase + (kt) * 64;                                   \
    const unsigned short* bB_ = Bbase + (kt) * 64;                                   \
    _Pragma("unroll")                                                                \
    for (int o_ = 0; o_ < 4; ++o_) {                                                 \
      int rg_ = wave * 4 + o_;                                                       \
      async_copy16(aB_ + (size_t)(rg_ * 8 + rl) * 512 + cs * 8, &As[S_][rg_ * 512]); \
      async_copy16(bB_ + (size_t)(rg_ * 8 + rl) * 512 + cs * 8, &Bs[S_][rg_ * 512]); \
    }                                                                                \
  } while (0)

  STAGE_BB(0, 0);

#pragma unroll 2
  for (int it = 0; it < 8; ++it) {
    const int S = it & 1;
    __syncthreads();                   // drains STAGE(it) [flew across compute(it-1)]
    if (it < 7) STAGE_BB(it + 1, S ^ 1);
    __builtin_amdgcn_sched_barrier(0); // keep the stage issue above compute

#pragma unroll
    for (int x = 0; x < 2; ++x) {
      bf16x8 a[4], bfr[4];
#pragma unroll
      for (int i = 0; i < 4; ++i) {
        int ra = wm + 16 * i + l15;
        a[i] = *reinterpret_cast<const bf16x8*>(&As[S][ra * 64 + (((x * 4 + quad) ^ (ra & 7)) << 3)]);
      }
#pragma unroll
      for (int j = 0; j < 4; ++j) {
        int rb = wn + 16 * j + l15;
        bfr[j] = *reinterpret_cast<const bf16x8*>(&Bs[S][rb * 64 + (((x * 4 + quad) ^ (rb & 7)) << 3)]);
      }
#pragma unroll
      for (int i = 0; i < 4; ++i)
#pragma unroll
        for (int j = 0; j < 4; ++j)
          acc[i][j] = __builtin_amdgcn_mfma_f32_16x16x32_bf16(a[i], bfr[j], acc[i][j], 0, 0, 0);
    }
  }
#undef STAGE_BB

#pragma unroll
  for (int i = 0; i < 4; ++i)
#pragma unroll
    for (int j = 0; j < 4; ++j)
#pragma unroll
      for (int r = 0; r < 4; ++r) {
        int m = m0 + wm + 16 * i + 4 * quad + r;
        int n = n0 + wn + 16 * j + l15;
        Y[(size_t)m * 512 + n] = __float2bfloat16(acc[i][j][r]);
      }
}

// ---------------------------------------------------------------- fused attention (swapped-operand), round-8 restructure
// 4 waves (256 thr), 64-s tiles, 4 s-chunks -> grid 512 (blk = bh*4+chunk).
// LDS 72 KB (qs 32 + vs 8 + pst 32) -> 2 independent blocks/CU: while one
// block stalls at __syncthreads, the other's waves run (same 8 waves/CU as
// before, but barriers no longer gate the whole CU). Wave w owns s-slice
// [16w,16w+16) of the 64-s tile; n-partition for PV: wave owns jt'=4w..4w+3.
__global__ __launch_bounds__(256, 2) void attn_kernel(const __hip_bfloat16* __restrict__ qg,
                                                      const __hip_bfloat16* __restrict__ kg,
                                                      const unsigned short* __restrict__ vcast,
                                                      float* __restrict__ accg,
                                                      float* __restrict__ rsg) {
  __shared__ unsigned short qs[256 * 64];    // q[n][c], chunk phys = cc ^ (n&7)   (32 KB)
  __shared__ unsigned short vs[64 * 64];     // v^T[c][s], chunk phys = sc ^ (c&7) (8 KB)
  __shared__ unsigned short pst[256 * 64];   // P[n][s],  chunk phys = sc ^ (n&7)  (32 KB)

  const int t = threadIdx.x;
  const int wave = t >> 6, lane = t & 63, l15 = lane & 15, quad = lane >> 4;
  const int blk = blockIdx.x, chunk = blk & 3, bh = blk >> 2, b = bh >> 3, h = bh & 7;
  const int l7 = l15 & 7;

  // ---- stage qs (once): 8 b128 per thread, coalesced
  {
    const unsigned short* qbase = (const unsigned short*)qg + (size_t)(b * 256) * 512 + h * 64;
#pragma unroll
    for (int i = 0; i < 8; ++i) {
      int lin = i * 256 + t;
      int n = lin >> 3, cc = lin & 7, phys = cc ^ (n & 7);
      bf16x8 v = *reinterpret_cast<const bf16x8*>(qbase + (size_t)n * 512 + cc * 8);
      *reinterpret_cast<bf16x8*>(&qs[n * 64 + phys * 8]) = v;
    }
  }

  const unsigned short* kbase = (const unsigned short*)kg + (size_t)(b * 4096 + chunk * 1024) * 512 + h * 64;
  const unsigned short* vbase = vcast + (size_t)(b * 4096 + chunk * 1024) * 512 + h * 64;

  // ---- prefetch k (regs) and v (regs) for it=0
  bf16x8 kc0 = *reinterpret_cast<const bf16x8*>(kbase + (size_t)(16 * wave + l15) * 512 + quad * 8);
  bf16x8 kc1 = *reinterpret_cast<const bf16x8*>(kbase + (size_t)(16 * wave + l15) * 512 + 32 + quad * 8);
  unsigned short vh[16];
#pragma unroll
  for (int half = 0; half < 2; ++half) {
    int sc = wave + 4 * half;                  // 0..7 s-chunks of the 64-s tile
#pragma unroll
    for (int j = 0; j < 8; ++j)
      vh[half * 8 + j] = vbase[(size_t)(sc * 8 + j) * 512 + lane];
  }

  union { bf16x8 f; int w[4]; } ones_u;
  ones_u.w[0] = 0x3F803F80; ones_u.w[1] = 0x3F803F80;
  ones_u.w[2] = 0x3F803F80; ones_u.w[3] = 0x3F803F80;
  const bf16x8 ones = ones_u.f;

  f32x4 oacc[4][4], rsacc[4];
#pragma unroll
  for (int i = 0; i < 4; ++i) {
    f32x4 z = {0.f, 0.f, 0.f, 0.f};
    rsacc[i] = z;
#pragma unroll
    for (int j = 0; j < 4; ++j) oacc[i][j] = z;
  }

  __syncthreads();   // qs visible

  for (int it = 0; it < 16; ++it) {
    // ---- QK^T (swapped): L[jt] = D[s16 x n16], A = k regs, B = q from LDS
    f32x4 L[16];
#pragma unroll
    for (int jt = 0; jt < 16; ++jt) { f32x4 z = {0.f, 0.f, 0.f, 0.f}; L[jt] = z; }
#pragma unroll
    for (int x = 0; x < 2; ++x) {
      bf16x8 kf = x ? kc1 : kc0;
#pragma unroll
      for (int jt = 0; jt < 16; ++jt) {
        bf16x8 bq = *reinterpret_cast<const bf16x8*>(
            &qs[(16 * jt + l15) * 64 + ((4 * x + quad) ^ l7) * 8]);
        L[jt] = __builtin_amdgcn_mfma_f32_16x16x32_bf16(kf, bq, L[jt], 0, 0, 0);
      }
    }

    // ---- prefetch next k (old regs dead)
    const int nit = (it < 15) ? it + 1 : 15;
    kc0 = *reinterpret_cast<const bf16x8*>(kbase + (size_t)(nit * 64 + 16 * wave + l15) * 512 + quad * 8);
    kc1 = *reinterpret_cast<const bf16x8*>(kbase + (size_t)(nit * 64 + 16 * wave + l15) * 512 + 32 + quad * 8);

    // ---- exp + within-wave column softmax (sum over n = jt in-lane + shfl over l15)
    float cs0 = 0.f, cs1 = 0.f, cs2 = 0.f, cs3 = 0.f;
#pragma unroll
    for (int jt = 0; jt < 16; ++jt) {
      float e0 = __expf(L[jt][0] * 0.125f);
      float e1 = __expf(L[jt][1] * 0.125f);
      float e2 = __expf(L[jt][2] * 0.125f);
      float e3 = __expf(L[jt][3] * 0.125f);
      L[jt][0] = e0; L[jt][1] = e1; L[jt][2] = e2; L[jt][3] = e3;
      cs0 += e0; cs1 += e1; cs2 += e2; cs3 += e3;
    }
#pragma unroll
    for (int m = 1; m <= 8; m <<= 1) {
      cs0 += __shfl_xor(cs0, m);
      cs1 += __shfl_xor(cs1, m);
      cs2 += __shfl_xor(cs2, m);
      cs3 += __shfl_xor(cs3, m);
    }
    const float ri0 = 1.0f / cs0, ri1 = 1.0f / cs1, ri2 = 1.0f / cs2, ri3 = 1.0f / cs3;

    __syncthreads();   // SYNC1: prev iteration's PV readers done with vs/pst

    // ---- stage vs from prefetched vh: one b128 per half, chunk-swizzled
#pragma unroll
    for (int half = 0; half < 2; ++half) {
      int sc = wave + 4 * half;
      uint4 w;
      w.x = (u32)vh[half * 8 + 0] | ((u32)vh[half * 8 + 1] << 16);
      w.y = (u32)vh[half * 8 + 2] | ((u32)vh[half * 8 + 3] << 16);
      w.z = (u32)vh[half * 8 + 4] | ((u32)vh[half * 8 + 5] << 16);
      w.w = (u32)vh[half * 8 + 6] | ((u32)vh[half * 8 + 7] << 16);
      *reinterpret_cast<uint4*>(&vs[lane * 64 + (sc ^ (lane & 7)) * 8]) = w;
    }

    // ---- write P[n][s] (A-layout rows), b64 chunk-swizzled
    {
      const int scw = 2 * wave + (quad >> 1);           // lane's s-chunk (0..7)
      const int half8 = (quad & 1) * 4;                 // b64 half within chunk
#pragma unroll
      for (int jt = 0; jt < 16; ++jt) {
        uint2 w;
        w.x = pkbf(L[jt][0] * ri0, L[jt][1] * ri1);
        w.y = pkbf(L[jt][2] * ri2, L[jt][3] * ri3);
        int row = 16 * jt + l15;
        *reinterpret_cast<uint2*>(&pst[row * 64 + ((scw ^ l7) * 8) + half8]) = w;
      }
    }

    __syncthreads();   // SYNC2: vs + pst visible

    // ---- prefetch next v (consumed next iteration)
#pragma unroll
    for (int half = 0; half < 2; ++half) {
      int sc = wave + 4 * half;
#pragma unroll
      for (int j = 0; j < 8; ++j)
        vh[half * 8 + j] = vbase[(size_t)(nit * 64 + sc * 8 + j) * 512 + lane];
    }

    // ---- PV + ones-rowsum, n-partitioned: wave owns jt' = 4w..4w+3
#pragma unroll
    for (int kc = 0; kc < 2; ++kc) {
      bf16x8 bv[4];
#pragma unroll
      for (int jc = 0; jc < 4; ++jc)
        bv[jc] = *reinterpret_cast<const bf16x8*>(
            &vs[(16 * jc + l15) * 64 + ((4 * kc + quad) ^ l7) * 8]);
#pragma unroll
      for (int jtl = 0; jtl < 4; ++jtl) {
        int rowp = 16 * (4 * wave + jtl) + l15;
        bf16x8 ap = *reinterpret_cast<const bf16x8*>(
            &pst[rowp * 64 + ((4 * kc + quad) ^ l7) * 8]);
#pragma unroll
        for (int jc = 0; jc < 4; ++jc)
          oacc[jtl][jc] = __builtin_amdgcn_mfma_f32_16x16x32_bf16(ap, bv[jc], oacc[jtl][jc], 0, 0, 0);
        rsacc[jtl] = __builtin_amdgcn_mfma_f32_16x16x32_bf16(ap, ones, rsacc[jtl], 0, 0, 0);
      }
    }
  }

  // ---- flush per-chunk partials (disjoint n per wave, disjoint chunk regions)
  float* rsp = rsg + chunk * 32768 + bh * 256;
  if (l15 == 0) {
#pragma unroll
    for (int jtl = 0; jtl < 4; ++jtl)
#pragma unroll
      for (int r = 0; r < 4; ++r)
        rsp[16 * (4 * wave + jtl) + 4 * quad + r] = rsacc[jtl][r];
  }
  float* ap_ = accg + (size_t)chunk * 2097152 + (size_t)bh * 16384;
#pragma unroll
  for (int jtl = 0; jtl < 4; ++jtl)
#pragma unroll
    for (int jc = 0; jc < 4; ++jc)
#pragma unroll
      for (int r = 0; r < 4; ++r)
        ap_[(16 * (4 * wave + jtl) + 4 * quad + r) * 64 + 16 * jc + l15] = oacc[jtl][jc][r];
}

// ---------------------------------------------------------------- finalize: sum 4 chunk partials, divide, write both outputs
__global__ __launch_bounds__(256) void finalize(const float* __restrict__ acc,
                                                const float* __restrict__ rs,
                                                float* __restrict__ out) {
  int g = blockIdx.x * 256 + threadIdx.x;     // 0 .. 524287 (x4 elements)
  int c = (g & 15) * 4, n = (g >> 4) & 255, bh = g >> 12;
  int e = g * 4;
  float4 v0 = *reinterpret_cast<const float4*>(&acc[e]);
  float4 v1 = *reinterpret_cast<const float4*>(&acc[e + 2097152]);
  float4 v2 = *reinterpret_cast<const float4*>(&acc[e + 2 * 2097152]);
  float4 v3 = *reinterpret_cast<const float4*>(&acc[e + 3 * 2097152]);
  int ri = bh * 256 + n;
  float r = rs[ri] + rs[32768 + ri] + rs[65536 + ri] + rs[98304 + ri];
  float inv = 1.0f / fmaxf(r, 1.0f);
  float4 o;
  o.x = (v0.x + v1.x + v2.x + v3.x) * inv;
  o.y = (v0.y + v1.y + v2.y + v3.y) * inv;
  o.z = (v0.z + v1.z + v2.z + v3.z) * inv;
  o.w = (v0.w + v1.w + v2.w + v3.w) * inv;
  int b = bh >> 3, h = bh & 7;
  size_t oi = ((size_t)(b * 256 + n)) * 512 + h * 64 + c;
  *reinterpret_cast<float4*>(&out[oi]) = o;
  *reinterpret_cast<float4*>(&out[oi + 2097152]) = o;
}

extern "C" void kernel_launch(void* const* d_in, const int* in_sizes, int n_in,
                              void* d_out, int out_size, void* d_ws, size_t ws_size,
                              hipStream_t stream) {
  const float* query = (const float*)d_in[0];   // [16,256,512]
  const float* key   = (const float*)d_in[1];   // [16,4096,512]
  const float* Wq    = (const float*)d_in[2];   // [512,512]
  const float* Wk    = (const float*)d_in[3];   // [512,512]
  float* out = (float*)d_out;
  char* ws = (char*)d_ws;

  // ws layout (bytes) — requires ~178 MB (d_ws evidenced 512 MiB by harness fills):
  unsigned short* WtQ = (unsigned short*)(ws);                 // 524288
  unsigned short* WtK = (unsigned short*)(ws + 524288);        // 524288
  __hip_bfloat16* qbf = (__hip_bfloat16*)(ws + 1048576);       // 4096*512*2   = 4194304
  __hip_bfloat16* kbf = (__hip_bfloat16*)(ws + 5242880);       // 65536*512*2  = 67108864
  float* accw = (float*)(ws + 72351744);                       // 4*2097152*4  = 33554432
  float* rsw  = (float*)(ws + 105906176);                      // 4*32768*4    = 524288
  unsigned short* kcast = (unsigned short*)(ws + 106430464);   // 65536*512*2  = 67108864
  unsigned short* qcast = (unsigned short*)(ws + 173539328);   // 4096*512*2   = 4194304
  // total: 177,733,632 bytes

  prep_w<<<17536, 256, 0, stream>>>(Wq, Wk, WtQ, WtK, key, kcast, query, qcast);
  gemm_bb<<<dim3(4, 544), 256, 0, stream>>>(kcast, WtK, kbf, qcast, WtQ, qbf);
  attn_kernel<<<512, 256, 0, stream>>>(qbf, kbf, kcast, accw, rsw);
  finalize<<<2048, 256, 0, stream>>>(accw, rsw, out);
}

// Round 9
// 306.299 us; speedup vs baseline: 1.0806x; 1.0739x over previous
//
#include <hip/hip_runtime.h>
#include <hip/hip_bf16.h>

// AssignAttention: B=16, N=256, S=4096, C=512, H=8, hd=64
// out[b,n,h*64+c] = sum_s softmax_n(q.kT/8)[n,s]/max(rowsum,1) * key[b,s,h*64+c]
// d_out = [out, out_style] (identical copies), fp32.

typedef __attribute__((ext_vector_type(8))) short bf16x8;
typedef __attribute__((ext_vector_type(4))) float f32x4;
typedef unsigned int u32;

__device__ __forceinline__ unsigned short f2bf(float f) {
  union { __hip_bfloat16 h; unsigned short u; } cv;
  cv.h = __float2bfloat16(f);
  return cv.u;
}

__device__ __forceinline__ u32 pkbf(float a, float b) {   // low=bf(a), high=bf(b)
  union { __hip_bfloat162 h; u32 u; } cv;
  cv.h = __float22bfloat162_rn(float2{a, b});
  return cv.u;
}

// async global->LDS, 16B per lane. LDS dest = wave-uniform base + lane*16.
__device__ __forceinline__ void async_copy16(const void* gptr, void* lptr) {
  __builtin_amdgcn_global_load_lds((const __attribute__((address_space(1))) u32*)gptr,
                                   (__attribute__((address_space(3))) u32*)lptr,
                                   16, 0, 0);
}

// ---------------------------------------------------------------- prep: Wt[n][k] = bf16(W[k][n])
__global__ __launch_bounds__(256) void prep_w(const float* __restrict__ Wq,
                                              const float* __restrict__ Wk,
                                              unsigned short* __restrict__ WtQ,
                                              unsigned short* __restrict__ WtK) {
  __shared__ float tile[64][65];
  const int blk = blockIdx.x;
  const float* W = (blk & 1) ? Wk : Wq;
  unsigned short* Wt = (blk & 1) ? WtK : WtQ;
  const int tb = blk >> 1;                     // 0..63
  const int k0 = (tb >> 3) * 64, n0 = (tb & 7) * 64;
  const int t = threadIdx.x;
  const int row = t >> 4, col4 = (t & 15) * 4;
#pragma unroll
  for (int i = 0; i < 4; ++i) {
    int r = i * 16 + row;
    float4 v = *reinterpret_cast<const float4*>(&W[(size_t)(k0 + r) * 512 + n0 + col4]);
    tile[r][col4 + 0] = v.x; tile[r][col4 + 1] = v.y;
    tile[r][col4 + 2] = v.z; tile[r][col4 + 3] = v.w;
  }
  __syncthreads();
#pragma unroll
  for (int i = 0; i < 4; ++i) {
    int r = i * 16 + row;                      // n-local output row
    short4 s;
    s.x = (short)f2bf(tile[col4 + 0][r]);
    s.y = (short)f2bf(tile[col4 + 1][r]);
    s.z = (short)f2bf(tile[col4 + 2][r]);
    s.w = (short)f2bf(tile[col4 + 3][r]);
    *reinterpret_cast<short4*>(&Wt[(size_t)(n0 + r) * 512 + k0 + col4]) = s;
  }
}

// ---------------------------------------------------------------- GEMM: Y[m][n] = bf16( X[m][:] @ Wt[n][:] )
// R4 structure (best measured for fp32-A: 86.5 us), merged q/k launch.
//  * A fp32->bf16 cvt BEFORE bar1 (overlaps prior compute); serial region is
//    4x ds_write_b128 only.
//  * Bs double-buffered DMA, next-tile loads issued after bar2 (fly across
//    compute, drained by next bar1's implicit vmcnt(0)).
//  * bijective XCD swizzle; merged grid 4x544 (tile<2048 -> key, else query).
__global__ __launch_bounds__(256, 3) void gemm_xw(const float* __restrict__ Xk,
                                                  const unsigned short* __restrict__ WtKp,
                                                  __hip_bfloat16* __restrict__ Yk,
                                                  const float* __restrict__ Xq,
                                                  const unsigned short* __restrict__ WtQp,
                                                  __hip_bfloat16* __restrict__ Yq) {
  __shared__ unsigned short As[128 * 64];        // bf16, chunk phys = cc ^ (r&7)  (16 KB)
  __shared__ unsigned short Bs[2][128 * 64];     // bf16, chunk phys = cc ^ (r&7)  (2x16 KB)
  const int t = threadIdx.x;
  const int wave = t >> 6, lane = t & 63, l15 = lane & 15, quad = lane >> 4;

  const int nwg = gridDim.x * gridDim.y;               // 2176, %8==0
  const int d = blockIdx.y * gridDim.x + blockIdx.x;
  const int tile = (d & 7) * (nwg >> 3) + (d >> 3);

  const float* X; const unsigned short* Wt; __hip_bfloat16* Y; int n0, m0;
  if (tile < 2048) { X = Xk; Wt = WtKp; Y = Yk; n0 = (tile & 3) * 128; m0 = (tile >> 2) * 128; }
  else { int u = tile - 2048; X = Xq; Wt = WtQp; Y = Yq; n0 = (u & 3) * 128; m0 = (u >> 2) * 128; }

  const int wm = (wave >> 1) * 64, wn = (wave & 1) * 64;
  const int b_rl = lane >> 3;                       // 0..7
  const int b_cs = (lane & 7) ^ b_rl;               // source chunk (row&7 == b_rl)
  const int a_r = t >> 3, a_cc = t & 7;             // A staging: row base, chunk col

  f32x4 acc[4][4];
#pragma unroll
  for (int i = 0; i < 4; ++i)
#pragma unroll
    for (int j = 0; j < 4; ++j) { f32x4 z = {0.f, 0.f, 0.f, 0.f}; acc[i][j] = z; }

  float4 f0[4], f1[4];

  // ---- prologue: issue tile-0 loads
  {
    const unsigned short* bBase = Wt + (size_t)n0 * 512;
#pragma unroll
    for (int o = 0; o < 4; ++o) {
      int rg = wave * 4 + o;
      async_copy16(bBase + (size_t)(rg * 8 + b_rl) * 512 + b_cs * 8, &Bs[0][rg * 512]);
    }
    const float* aBase = X + (size_t)m0 * 512;
#pragma unroll
    for (int i = 0; i < 4; ++i) {
      const float* p = aBase + (size_t)(i * 32 + a_r) * 512 + a_cc * 8;
      f0[i] = *reinterpret_cast<const float4*>(p);
      f1[i] = *reinterpret_cast<const float4*>(p + 4);
    }
  }

  for (int k0 = 0; k0 < 512; k0 += 64) {
    const int buf = (k0 >> 6) & 1;

    // ---- cvt prefetched A regs (before bar1)
    uint4 abf[4];
#pragma unroll
    for (int i = 0; i < 4; ++i) {
      abf[i].x = pkbf(f0[i].x, f0[i].y);
      abf[i].y = pkbf(f0[i].z, f0[i].w);
      abf[i].z = pkbf(f1[i].x, f1[i].y);
      abf[i].w = pkbf(f1[i].z, f1[i].w);
    }

    __syncthreads();   // bar1: prev compute done with LDS; drains DMA(k)+av(k)

    // ---- publish A: 4x ds_write_b128, swizzled chunks (conflict-free)
#pragma unroll
    for (int i = 0; i < 4; ++i) {
      int r = i * 32 + a_r;
      *reinterpret_cast<uint4*>(&As[r * 64 + ((a_cc ^ (r & 7)) << 3)]) = abf[i];
    }
    __syncthreads();   // bar2: As + Bs[buf] visible

    // ---- issue NEXT tile's loads (in flight during compute below)
    if (k0 < 448) {
      const int k1 = k0 + 64;
      const unsigned short* bBase = Wt + (size_t)n0 * 512 + k1;
#pragma unroll
      for (int o = 0; o < 4; ++o) {
        int rg = wave * 4 + o;
        async_copy16(bBase + (size_t)(rg * 8 + b_rl) * 512 + b_cs * 8, &Bs[buf ^ 1][rg * 512]);
      }
      const float* aBase = X + (size_t)m0 * 512 + k1;
#pragma unroll
      for (int i = 0; i < 4; ++i) {
        const float* p = aBase + (size_t)(i * 32 + a_r) * 512 + a_cc * 8;
        f0[i] = *reinterpret_cast<const float4*>(p);
        f1[i] = *reinterpret_cast<const float4*>(p + 4);
      }
    }
    __builtin_amdgcn_sched_barrier(0);   // don't let the prefetch sink into/below compute

    // ---- compute tile k from As / Bs[buf]
#pragma unroll
    for (int x = 0; x < 2; ++x) {
      bf16x8 a[4], bfr[4];
#pragma unroll
      for (int i = 0; i < 4; ++i) {
        int ra = wm + 16 * i + l15;
        a[i] = *reinterpret_cast<const bf16x8*>(&As[ra * 64 + (((x * 4 + quad) ^ (ra & 7)) << 3)]);
      }
#pragma unroll
      for (int j = 0; j < 4; ++j) {
        int rb = wn + 16 * j + l15;
        bfr[j] = *reinterpret_cast<const bf16x8*>(&Bs[buf][rb * 64 + (((x * 4 + quad) ^ (rb & 7)) << 3)]);
      }
#pragma unroll
      for (int i = 0; i < 4; ++i)
#pragma unroll
        for (int j = 0; j < 4; ++j)
          acc[i][j] = __builtin_amdgcn_mfma_f32_16x16x32_bf16(a[i], bfr[j], acc[i][j], 0, 0, 0);
    }
  }
#pragma unroll
  for (int i = 0; i < 4; ++i)
#pragma unroll
    for (int j = 0; j < 4; ++j)
#pragma unroll
      for (int r = 0; r < 4; ++r) {
        int m = m0 + wm + 16 * i + 4 * quad + r;
        int n = n0 + wn + 16 * j + l15;
        Y[(size_t)m * 512 + n] = __float2bfloat16(acc[i][j][r]);
      }
}

// ---------------------------------------------------------------- fused attention (swapped-operand), R7 structure + q-half-in-regs
// grid 256 (blk = bh*2 + chunk), 512 threads (8 waves), 16 iterations x 128 s.
// LDS-throughput fix: the x=0 half of the q B-fragments (identical every
// iteration) is held in registers (qr[16], 64 VGPR, loaded once) -> removes
// 16 of 32 qs ds_read_b128 per wave per iteration.
__global__ __launch_bounds__(512, 2) void attn_kernel(const __hip_bfloat16* __restrict__ qg,
                                                      const __hip_bfloat16* __restrict__ kg,
                                                      const float* __restrict__ keyg,
                                                      float* __restrict__ accg,
                                                      float* __restrict__ rsg) {
  __shared__ unsigned short qs[256 * 64];    // q[n][c], 16B-chunk phys = cc ^ (n&7)   (32 KB)
  __shared__ unsigned short vs[64 * 128];    // v^T[c][s], chunk phys = sc ^ (c&7)     (16 KB)
  __shared__ unsigned short pst[256 * 128];  // P[n][s],  chunk phys = sc ^ (n&7)      (64 KB)

  const int t = threadIdx.x;
  const int wave = t >> 6, lane = t & 63, l15 = lane & 15, quad = lane >> 4;
  const int blk = blockIdx.x, chunk = blk & 1, bh = blk >> 1, b = bh >> 3, h = bh & 7;
  const int l7 = l15 & 7;

  // ---- stage qs (once): 4 b128 per thread, coalesced 128B segments
  {
    const unsigned short* qbase = (const unsigned short*)qg + (size_t)(b * 256) * 512 + h * 64;
#pragma unroll
    for (int i = 0; i < 4; ++i) {
      int lin = i * 512 + t;
      int n = lin >> 3, cc = lin & 7, phys = cc ^ (n & 7);
      bf16x8 v = *reinterpret_cast<const bf16x8*>(qbase + (size_t)n * 512 + cc * 8);
      *reinterpret_cast<bf16x8*>(&qs[n * 64 + phys * 8]) = v;
    }
  }

  const unsigned short* kbase = (const unsigned short*)kg + (size_t)(b * 4096 + chunk * 2048) * 512 + h * 64;
  const float* vbase = keyg + (size_t)(b * 4096 + chunk * 2048) * 512 + h * 64;

  // ---- prefetch k (regs) and v (regs) for it=0
  bf16x8 kc0 = *reinterpret_cast<const bf16x8*>(kbase + (size_t)(16 * wave + l15) * 512 + quad * 8);
  bf16x8 kc1 = *reinterpret_cast<const bf16x8*>(kbase + (size_t)(16 * wave + l15) * 512 + 32 + quad * 8);
  float vbuf[16];
#pragma unroll
  for (int half = 0; half < 2; ++half) {
    int sc = wave + 8 * half;
#pragma unroll
    for (int j = 0; j < 8; ++j)
      vbuf[half * 8 + j] = vbase[(size_t)(sc * 8 + j) * 512 + lane];
  }

  union { bf16x8 f; int w[4]; } ones_u;
  ones_u.w[0] = 0x3F803F80; ones_u.w[1] = 0x3F803F80;
  ones_u.w[2] = 0x3F803F80; ones_u.w[3] = 0x3F803F80;
  const bf16x8 ones = ones_u.f;

  f32x4 oacc[2][4], rsacc[2];
#pragma unroll
  for (int i = 0; i < 2; ++i) {
    f32x4 z = {0.f, 0.f, 0.f, 0.f};
    rsacc[i] = z;
#pragma unroll
    for (int j = 0; j < 4; ++j) oacc[i][j] = z;
  }

  __syncthreads();   // qs visible

  // ---- load x=0 half of q B-fragments into registers ONCE (64 VGPR)
  bf16x8 qr[16];
#pragma unroll
  for (int jt = 0; jt < 16; ++jt)
    qr[jt] = *reinterpret_cast<const bf16x8*>(&qs[(16 * jt + l15) * 64 + (quad ^ l7) * 8]);

  for (int it = 0; it < 16; ++it) {
    // ---- QK^T (swapped): L[jt] = D[s16 x n16], A = k regs, B = q (regs x=0, LDS x=1)
    f32x4 L[16];
#pragma unroll
    for (int jt = 0; jt < 16; ++jt) { f32x4 z = {0.f, 0.f, 0.f, 0.f}; L[jt] = z; }
#pragma unroll
    for (int jt = 0; jt < 16; ++jt)
      L[jt] = __builtin_amdgcn_mfma_f32_16x16x32_bf16(kc0, qr[jt], L[jt], 0, 0, 0);
#pragma unroll
    for (int jt = 0; jt < 16; ++jt) {
      bf16x8 bq = *reinterpret_cast<const bf16x8*>(
          &qs[(16 * jt + l15) * 64 + ((4 + quad) ^ l7) * 8]);
      L[jt] = __builtin_amdgcn_mfma_f32_16x16x32_bf16(kc1, bq, L[jt], 0, 0, 0);
    }

    // ---- prefetch next k (old regs dead)
    const int nit = (it < 15) ? it + 1 : 15;
    kc0 = *reinterpret_cast<const bf16x8*>(kbase + (size_t)(nit * 128 + 16 * wave + l15) * 512 + quad * 8);
    kc1 = *reinterpret_cast<const bf16x8*>(kbase + (size_t)(nit * 128 + 16 * wave + l15) * 512 + 32 + quad * 8);

    // ---- exp + within-wave column softmax (sum over n = jt in-lane + shfl over l15)
    float cs0 = 0.f, cs1 = 0.f, cs2 = 0.f, cs3 = 0.f;
#pragma unroll
    for (int jt = 0; jt < 16; ++jt) {
      float e0 = __expf(L[jt][0] * 0.125f);
      float e1 = __expf(L[jt][1] * 0.125f);
      float e2 = __expf(L[jt][2] * 0.125f);
      float e3 = __expf(L[jt][3] * 0.125f);
      L[jt][0] = e0; L[jt][1] = e1; L[jt][2] = e2; L[jt][3] = e3;
      cs0 += e0; cs1 += e1; cs2 += e2; cs3 += e3;
    }
#pragma unroll
    for (int m = 1; m <= 8; m <<= 1) {
      cs0 += __shfl_xor(cs0, m);
      cs1 += __shfl_xor(cs1, m);
      cs2 += __shfl_xor(cs2, m);
      cs3 += __shfl_xor(cs3, m);
    }
    const float ri0 = 1.0f / cs0, ri1 = 1.0f / cs1, ri2 = 1.0f / cs2, ri3 = 1.0f / cs3;

    __syncthreads();   // SYNC1: prev iteration's PV readers done with vs/pst

    // ---- stage vs from prefetched vbuf: one b128 per half, chunk-swizzled
#pragma unroll
    for (int half = 0; half < 2; ++half) {
      int sc = wave + 8 * half;
      uint4 w;
      w.x = pkbf(vbuf[half * 8 + 0], vbuf[half * 8 + 1]);
      w.y = pkbf(vbuf[half * 8 + 2], vbuf[half * 8 + 3]);
      w.z = pkbf(vbuf[half * 8 + 4], vbuf[half * 8 + 5]);
      w.w = pkbf(vbuf[half * 8 + 6], vbuf[half * 8 + 7]);
      *reinterpret_cast<uint4*>(&vs[lane * 128 + (sc ^ (lane & 7)) * 8]) = w;
    }

    // ---- write P[n][s] (A-layout rows), b64 chunk-swizzled
    {
      const int scw = 2 * wave + (quad >> 1);           // 16B-chunk of this lane's s
      const int half8 = (quad & 1) * 4;                 // b64 half within chunk
#pragma unroll
      for (int jt = 0; jt < 16; ++jt) {
        uint2 w;
        w.x = pkbf(L[jt][0] * ri0, L[jt][1] * ri1);
        w.y = pkbf(L[jt][2] * ri2, L[jt][3] * ri3);
        int row = 16 * jt + l15;
        *reinterpret_cast<uint2*>(&pst[row * 128 + ((scw ^ l7) * 8) + half8]) = w;
      }
    }

    __syncthreads();   // SYNC2: vs + pst visible

    // ---- prefetch next v (consumed next iteration)
#pragma unroll
    for (int half = 0; half < 2; ++half) {
      int sc = wave + 8 * half;
#pragma unroll
      for (int j = 0; j < 8; ++j)
        vbuf[half * 8 + j] = vbase[(size_t)(nit * 128 + sc * 8 + j) * 512 + lane];
    }

    // ---- PV + ones-rowsum, n-partitioned: wave owns jt' = 2w, 2w+1
#pragma unroll
    for (int kc = 0; kc < 4; ++kc) {
      bf16x8 bv[4];
#pragma unroll
      for (int jc = 0; jc < 4; ++jc)
        bv[jc] = *reinterpret_cast<const bf16x8*>(
            &vs[(16 * jc + l15) * 128 + ((4 * kc + quad) ^ l7) * 8]);
#pragma unroll
      for (int jtl = 0; jtl < 2; ++jtl) {
        int rowp = 16 * (2 * wave + jtl) + l15;
        bf16x8 ap = *reinterpret_cast<const bf16x8*>(
            &pst[rowp * 128 + ((4 * kc + quad) ^ l7) * 8]);
#pragma unroll
        for (int jc = 0; jc < 4; ++jc)
          oacc[jtl][jc] = __builtin_amdgcn_mfma_f32_16x16x32_bf16(ap, bv[jc], oacc[jtl][jc], 0, 0, 0);
        rsacc[jtl] = __builtin_amdgcn_mfma_f32_16x16x32_bf16(ap, ones, rsacc[jtl], 0, 0, 0);
      }
    }
  }

  // ---- flush per-chunk partials (disjoint n per wave, disjoint chunk regions)
  float* rsp = rsg + chunk * 32768 + bh * 256;
  if (l15 == 0) {
#pragma unroll
    for (int jtl = 0; jtl < 2; ++jtl)
#pragma unroll
      for (int r = 0; r < 4; ++r)
        rsp[16 * (2 * wave + jtl) + 4 * quad + r] = rsacc[jtl][r];
  }
  float* ap_ = accg + (size_t)chunk * 2097152 + (size_t)bh * 16384;
#pragma unroll
  for (int jtl = 0; jtl < 2; ++jtl)
#pragma unroll
    for (int jc = 0; jc < 4; ++jc)
#pragma unroll
      for (int r = 0; r < 4; ++r)
        ap_[(16 * (2 * wave + jtl) + 4 * quad + r) * 64 + 16 * jc + l15] = oacc[jtl][jc][r];
}

// ---------------------------------------------------------------- finalize: divide + write both outputs (float4)
__global__ __launch_bounds__(256) void finalize(const float* __restrict__ acc,
                                                const float* __restrict__ rs,
                                                float* __restrict__ out) {
  int g = blockIdx.x * 256 + threadIdx.x;     // 0 .. 524287 (x4 elements)
  int c = (g & 15) * 4, n = (g >> 4) & 255, bh = g >> 12;
  int e = g * 4;
  float4 v0 = *reinterpret_cast<const float4*>(&acc[e]);
  float4 v1 = *reinterpret_cast<const float4*>(&acc[e + 2097152]);
  float r = rs[bh * 256 + n] + rs[32768 + bh * 256 + n];
  float inv = 1.0f / fmaxf(r, 1.0f);
  float4 o;
  o.x = (v0.x + v1.x) * inv; o.y = (v0.y + v1.y) * inv;
  o.z = (v0.z + v1.z) * inv; o.w = (v0.w + v1.w) * inv;
  int b = bh >> 3, h = bh & 7;
  size_t oi = ((size_t)(b * 256 + n)) * 512 + h * 64 + c;
  *reinterpret_cast<float4*>(&out[oi]) = o;
  *reinterpret_cast<float4*>(&out[oi + 2097152]) = o;
}

extern "C" void kernel_launch(void* const* d_in, const int* in_sizes, int n_in,
                              void* d_out, int out_size, void* d_ws, size_t ws_size,
                              hipStream_t stream) {
  const float* query = (const float*)d_in[0];   // [16,256,512]
  const float* key   = (const float*)d_in[1];   // [16,4096,512]
  const float* Wq    = (const float*)d_in[2];   // [512,512]
  const float* Wk    = (const float*)d_in[3];   // [512,512]
  float* out = (float*)d_out;
  char* ws = (char*)d_ws;

  // ws layout (bytes):
  unsigned short* WtQ = (unsigned short*)(ws);                 // 512*512*2   = 524288
  unsigned short* WtK = (unsigned short*)(ws + 524288);        // 524288
  __hip_bfloat16* qbf = (__hip_bfloat16*)(ws + 1048576);       // 4096*512*2  = 4194304
  __hip_bfloat16* kbf = (__hip_bfloat16*)(ws + 5242880);       // 65536*512*2 = 67108864
  float* accw = (float*)(ws + 72351744);                       // 2*128*256*64*4 = 16777216
  float* rsw  = (float*)(ws + 89128960);                       // 2*128*256*4    = 262144
  // total: 89,391,104 bytes

  prep_w<<<128, 256, 0, stream>>>(Wq, Wk, WtQ, WtK);
  gemm_xw<<<dim3(4, 544), 256, 0, stream>>>(key, WtK, kbf, query, WtQ, qbf);  // merged k+q GEMM
  attn_kernel<<<256, 512, 0, stream>>>(qbf, kbf, key, accw, rsw);
  finalize<<<2048, 256, 0, stream>>>(accw, rsw, out);
}